// Round 9
// baseline (361.667 us; speedup 1.0000x reference)
//
#include <hip/hip_runtime.h>

// ---------------------------------------------------------------------------
// SpatialSatCrossAttention (MS deformable attention, 6 cams, 10000 queries)
// R16 = R15 resubmit (previous bench failed on container acquisition, not
//     kernel). Instrumentation round: sample_k split by QUERY range
//     (4 x 2500q, zero duplication) and gemm_vqk split into gemm_v / gemm_qk
//     so the slowest tail kernel MUST surface in the top-5 with its exact
//     duration. GEMM internals / prep_w / gemm_out are R12-proven, untouched.
// Launches (8):
//   1. prep_w     : weight mats -> Wt[n][k] bf16
//   2. gemm_v     : vproj = value @ value_W + b (f16 out, 510 blocks)
//   3. gemm_qk    : qkcat = query @ [off|attw]_W (bf16 out, 474 blocks)
//   4-7. sample_k : deformable bilinear sampling, queries [q0, q0+2500)
//   8. gemm_out   : out = slots @ out_W + out_b + query (f32 d_out)
// ---------------------------------------------------------------------------

typedef unsigned short ushort_t;
typedef unsigned int uint_t;
typedef __attribute__((ext_vector_type(8))) short bf16x8;
typedef __attribute__((ext_vector_type(4))) float f32x4;
typedef __attribute__((ext_vector_type(2))) _Float16 f16x2;

__device__ __forceinline__ float bf2f(ushort_t u) {
    return __uint_as_float(((uint_t)u) << 16);
}
__device__ __forceinline__ ushort_t f2bf(float f) {
    uint_t i = __float_as_uint(f);
    uint_t r = i + 0x7fffu + ((i >> 16) & 1u);   // round-to-nearest-even
    return (ushort_t)(r >> 16);
}
// 8x f32 -> 8x bf16 via v_cvt_pk_bf16_f32 (RNE)
__device__ __forceinline__ bf16x8 pack8(float4 v0, float4 v1) {
    union { uint_t u[4]; bf16x8 v; } r;
    asm("v_cvt_pk_bf16_f32 %0, %1, %2" : "=v"(r.u[0]) : "v"(v0.x), "v"(v0.y));
    asm("v_cvt_pk_bf16_f32 %0, %1, %2" : "=v"(r.u[1]) : "v"(v0.z), "v"(v0.w));
    asm("v_cvt_pk_bf16_f32 %0, %1, %2" : "=v"(r.u[2]) : "v"(v1.x), "v"(v1.y));
    asm("v_cvt_pk_bf16_f32 %0, %1, %2" : "=v"(r.u[3]) : "v"(v1.z), "v"(v1.w));
    return r.v;
}
__device__ __forceinline__ ushort_t f2h(float f) {
    union { _Float16 h; ushort_t u; } cv;
    cv.h = (_Float16)f;
    return cv.u;
}

// acch[0..3] (packed f16x2, 8 channels) += wp(f16x2 dup) * f16x8(v)
__device__ __forceinline__ void pk_fma8(uint_t* a, uint_t wp, const uint4& v) {
    asm("v_pk_fma_f16 %0, %1, %2, %0" : "+v"(a[0]) : "v"(wp), "v"(v.x));
    asm("v_pk_fma_f16 %0, %1, %2, %0" : "+v"(a[1]) : "v"(wp), "v"(v.y));
    asm("v_pk_fma_f16 %0, %1, %2, %0" : "+v"(a[2]) : "v"(wp), "v"(v.z));
    asm("v_pk_fma_f16 %0, %1, %2, %0" : "+v"(a[3]) : "v"(wp), "v"(v.w));
}

// ---------------------------------------------------------------------------
// prep_w: weight transpose+convert only. W[k][N] f32 -> T[n][256] bf16.
// grid (8,16,4): z=0 value_W, z=1 out_W, z=2 off_W(512), z=3 attw_W.
// ---------------------------------------------------------------------------
__global__ __launch_bounds__(256) void prep_w(
    const float* __restrict__ Wv, const float* __restrict__ Wo,
    const float* __restrict__ Wf, const float* __restrict__ Wa,
    ushort_t* __restrict__ Tv, ushort_t* __restrict__ To,
    ushort_t* __restrict__ Tqk) {
    const int z = blockIdx.z;
    const float* W;
    ushort_t* T;
    int N;
    if (z == 0)      { W = Wv; T = Tv;              N = 256; }
    else if (z == 1) { W = Wo; T = To;              N = 256; }
    else if (z == 2) { W = Wf; T = Tqk;             N = 512; }
    else             { W = Wa; T = Tqk + 512 * 256; N = 256; }
    const int n0 = blockIdx.y * 32;
    if (n0 >= N) return;
    const int k0 = blockIdx.x * 32;

    __shared__ float tile[32][33];
    const int tx = threadIdx.x & 31;
    const int ty = threadIdx.x >> 5;   // 0..7
    #pragma unroll
    for (int r = 0; r < 4; ++r) {
        const int k = ty + r * 8;
        tile[k][tx] = W[(size_t)(k0 + k) * N + n0 + tx];
    }
    __syncthreads();
    #pragma unroll
    for (int r = 0; r < 4; ++r) {
        const int n = ty + r * 8;
        T[(size_t)(n0 + n) * 256 + k0 + tx] = f2bf(tile[tx][n]);
    }
}

// ---------------------------------------------------------------------------
// MFMA GEMM body: C[M,N] = A[M,256] @ Wt^T + bias (+resid).
// AF32: A is f32, converted to bf16 during LDS staging; else A is bf16.
// OUT_MODE: 0 = f32, 1 = bf16, 2 = f16.
// Astride: element stride between A rows (slots live embedded in qkcat).
// Wt bf16 [N][256]. N multiple of 128. 256 threads, 128x128 tile.
// ---------------------------------------------------------------------------
template <bool AF32, int OUT_MODE, bool RESID>
__device__ __forceinline__ void gemm_body(
    ushort_t (*sA)[128][32], ushort_t (*sB)[128][32],
    const void* __restrict__ Av, int Astride, const ushort_t* __restrict__ Wt,
    const float* __restrict__ bias0, const float* __restrict__ bias1, int split,
    const float* __restrict__ resid, void* __restrict__ Cv,
    int M, int N, int bx, int by) {
    const int m0 = bx * 128;
    const int n0 = by * 128;
    const int t    = threadIdx.x;
    const int lane = t & 63;
    const int w    = t >> 6;
    const int wr   = w >> 1, wc = w & 1;

    const int srow = t >> 2;          // 0..63
    const int skof = (t & 3) * 8;     // 0,8,16,24

    const bool am0 = (m0 + srow) < M;
    const bool am1 = (m0 + 64 + srow) < M;
    const float*    Af0 = (const float*)Av + (size_t)(m0 + srow) * Astride + skof;
    const float*    Af1 = Af0 + (size_t)64 * Astride;
    const ushort_t* Ab0 = (const ushort_t*)Av + (size_t)(m0 + srow) * Astride + skof;
    const ushort_t* Ab1 = Ab0 + (size_t)64 * Astride;
    const ushort_t* Bp0 = Wt + (size_t)(n0 + srow) * 256 + skof;
    const ushort_t* Bp1 = Bp0 + (size_t)64 * 256;

    const bf16x8 zz = {0, 0, 0, 0, 0, 0, 0, 0};

    auto loadA = [&](const float* af, const ushort_t* ab, int ko, bool ok) -> bf16x8 {
        if (!ok) return zz;
        if (AF32) {
            const float4 v0 = *(const float4*)(af + ko);
            const float4 v1 = *(const float4*)(af + ko + 4);
            return pack8(v0, v1);
        }
        return *(const bf16x8*)(ab + ko);
    };

    f32x4 acc[4][4];
    #pragma unroll
    for (int i = 0; i < 4; ++i)
        #pragma unroll
        for (int j = 0; j < 4; ++j)
            acc[i][j] = (f32x4){0.f, 0.f, 0.f, 0.f};

    // prologue: tile 0 -> LDS[0]
    {
        const bf16x8 a0 = loadA(Af0, Ab0, 0, am0);
        const bf16x8 a1 = loadA(Af1, Ab1, 0, am1);
        const bf16x8 b0 = *(const bf16x8*)(Bp0);
        const bf16x8 b1 = *(const bf16x8*)(Bp1);
        *(bf16x8*)(&sA[0][srow][skof])      = a0;
        *(bf16x8*)(&sA[0][64 + srow][skof]) = a1;
        *(bf16x8*)(&sB[0][srow][skof])      = b0;
        *(bf16x8*)(&sB[0][64 + srow][skof]) = b1;
    }
    __syncthreads();

    const int rl = lane & 15;
    const int kq = (lane >> 4) * 8;

    for (int k = 0; k < 8; ++k) {
        const int buf = k & 1;

        bf16x8 na0 = zz, na1 = zz, nb0 = zz, nb1 = zz;
        if (k < 7) {
            const int ko = (k + 1) * 32;
            na0 = loadA(Af0, Ab0, ko, am0);
            na1 = loadA(Af1, Ab1, ko, am1);
            nb0 = *(const bf16x8*)(Bp0 + ko);
            nb1 = *(const bf16x8*)(Bp1 + ko);
        }

        bf16x8 af[4], bfr[4];
        #pragma unroll
        for (int i = 0; i < 4; ++i)
            af[i] = *(const bf16x8*)(&sA[buf][wr * 64 + i * 16 + rl][kq]);
        #pragma unroll
        for (int j = 0; j < 4; ++j)
            bfr[j] = *(const bf16x8*)(&sB[buf][wc * 64 + j * 16 + rl][kq]);
        #pragma unroll
        for (int i = 0; i < 4; ++i)
            #pragma unroll
            for (int j = 0; j < 4; ++j)
                acc[i][j] = __builtin_amdgcn_mfma_f32_16x16x32_bf16(
                    af[i], bfr[j], acc[i][j], 0, 0, 0);

        if (k < 7) {
            __syncthreads();
            *(bf16x8*)(&sA[buf ^ 1][srow][skof])      = na0;
            *(bf16x8*)(&sA[buf ^ 1][64 + srow][skof]) = na1;
            *(bf16x8*)(&sB[buf ^ 1][srow][skof])      = nb0;
            *(bf16x8*)(&sB[buf ^ 1][64 + srow][skof]) = nb1;
            __syncthreads();
        }
    }

    // --- epilogue: C/D layout col=lane&15, row=(lane>>4)*4+reg (m89) ---
    const int col_l = lane & 15;
    const int rq    = (lane >> 4) * 4;
    #pragma unroll
    for (int j = 0; j < 4; ++j) {
        const int gn = n0 + wc * 64 + j * 16 + col_l;
        const float bj = (gn < split) ? bias0[gn] : bias1[gn - split];
        #pragma unroll
        for (int i = 0; i < 4; ++i) {
            #pragma unroll
            for (int r = 0; r < 4; ++r) {
                const int gm = m0 + wr * 64 + i * 16 + rq + r;
                if (gm >= M) continue;
                float v = acc[i][j][r] + bj;
                if (RESID) v += resid[(size_t)gm * N + gn];
                if (OUT_MODE == 1)
                    ((ushort_t*)Cv)[(size_t)gm * N + gn] = f2bf(v);
                else if (OUT_MODE == 2)
                    ((ushort_t*)Cv)[(size_t)gm * N + gn] = f2h(v);
                else
                    ((float*)Cv)[(size_t)gm * N + gn] = v;
            }
        }
    }
}

// value projection GEMM: 510 blocks (255 m x 2 n), f16 out.
__global__ __launch_bounds__(256) void gemm_v_k(
    const float* __restrict__ value, const ushort_t* __restrict__ value_Wt,
    const float* __restrict__ value_b, ushort_t* __restrict__ vproj) {
    __shared__ ushort_t sA[2][128][32];
    __shared__ ushort_t sB[2][128][32];
    const int b = blockIdx.x;
    gemm_body<true, 2, false>(sA, sB, value, 256, value_Wt, value_b, value_b,
                              256, nullptr, (void*)vproj, 32640, 256,
                              b % 255, b / 255);
}

// offset/attw projection GEMM: 474 blocks (79 m x 6 n), bf16 out.
__global__ __launch_bounds__(256) void gemm_qk_k(
    const float* __restrict__ query, const ushort_t* __restrict__ qk_Wt,
    const float* __restrict__ off_b, const float* __restrict__ attw_b,
    ushort_t* __restrict__ qkcat) {
    __shared__ ushort_t sA[2][128][32];
    __shared__ ushort_t sB[2][128][32];
    const int b = blockIdx.x;
    gemm_body<true, 1, false>(sA, sB, query, 256, qk_Wt, off_b, attw_b,
                              512, nullptr, (void*)qkcat, 10000, 768,
                              b % 79, b / 79);
}

__global__ __launch_bounds__(256) void gemm_out_k(
    const ushort_t* __restrict__ slots,   // = qkcat + 512, row stride 768
    const ushort_t* __restrict__ out_Wt,
    const float* __restrict__ out_b, const float* __restrict__ query,
    float* __restrict__ out) {
    __shared__ ushort_t sA[2][128][32];
    __shared__ ushort_t sB[2][128][32];
    gemm_body<false, 0, true>(sA, sB, slots, 768, out_Wt, out_b, out_b, 256,
                              query, (void*)out, 10000, 256,
                              blockIdx.x, blockIdx.y);
}

// ---------------------------------------------------------------------------
// Deformable sampling (R12 structure). grid (2500, 2), 128 thr, 4 heads
// (hb = blockIdx.y*4); 4 dispatches cover query ranges [q0, q0+2500).
// Barrier-free, LDS-free; slice reduction via shfl_xor tree; slots packed
// to one 16B store per writer lane into qkcat[:,512:768).
// ---------------------------------------------------------------------------
__global__ __launch_bounds__(128) void sample_k(
    ushort_t* __restrict__ qkcat,        // bf16 [10000, 768]
    const float* __restrict__ refp,      // f32 [6,1,10000,4,2]
    const int* __restrict__ vox,         // int32 [6,1,10000,4]
    const ushort_t* __restrict__ vproj,  // f16 [6*5440, 256]
    int q0) {                            // query range base
    const int q    = q0 + blockIdx.x;
    const int hb   = blockIdx.y << 2;    // head base: 0 or 4
    const int tid  = threadIdx.x;        // 0..127
    const int lane = tid & 63;
    const int h    = hb + (tid >> 5);    // this thread's head
    const int lp   = tid & 31;           // setup role: (lvl,p)
    const int slice = (tid >> 2) & 7;    // gather role
    const int g     = tid & 3;           // gather role: channels g*8..g*8+7

    // ---- validity: lanes 0..5 load their cam's vox row, broadcast ----
    int mm = 0;
    if (lane < 6) {
        const uint4 vm = *(const uint4*)(vox + ((lane * 10000 + q) << 2));
        mm = (int)(vm.x | vm.y | vm.z | vm.w);
    }
    float sv[6];
    #pragma unroll
    for (int c = 0; c < 6; ++c) sv[c] = __shfl(mm, c) ? 1.0f : 0.0f;
    const float cnt = sv[0] + sv[1] + sv[2] + sv[3] + sv[4] + sv[5];

    // ---- softmax over 32 (lvl,p) entries within this head ----
    const float a = bf2f(qkcat[(size_t)q * 768 + 512 + h * 32 + lp]);
    float mx = a;
    #pragma unroll
    for (int o = 16; o >= 1; o >>= 1) mx = fmaxf(mx, __shfl_xor(mx, o));
    const float e = __expf(a - mx);
    float se = e;
    #pragma unroll
    for (int o = 16; o >= 1; o >>= 1) se += __shfl_xor(se, o);
    const float aw = e / se;

    // ---- camera-independent part of this thread's sample location ----
    const int lvl = lp >> 3;
    const int p   = lp & 7;
    const int dd  = p & 3;
    const int   Sarr[4]   = {64, 32, 16, 8};
    const int   Lstart[4] = {0, 4096, 5120, 5376};
    const int   S  = Sarr[lvl];
    const float Sf = (float)S;
    const int   lstart = Lstart[lvl];
    const int   hoff   = h << 6;     // head byte offset within a row (32ch*2B)
    const float ox = bf2f(qkcat[(size_t)q * 768 + h * 64 + lvl * 16 + p * 2 + 0]) / Sf;
    const float oy = bf2f(qkcat[(size_t)q * 768 + h * 64 + lvl * 16 + p * 2 + 1]) / Sf;

    float acc[8] = {0.f, 0.f, 0.f, 0.f, 0.f, 0.f, 0.f, 0.f};
    const char* vpb = (const char*)vproj;
    const int goff = g << 4;             // 4 lanes x 16B within 64B chunk
    const int srcbase = (lane & 32) + slice * 4;

    for (int c = 0; c < 6; ++c) {
        if (sv[c] == 0.0f) continue;     // block-uniform branch

        // ---- setup: corner BYTE offsets + packed-f16 weights ----
        int    cb[4];
        uint_t cwp[4];
        {
            const int cbase = c * 5440 + lstart;
            const int rbase = ((c * 10000 + q) * 4 + dd) * 2;
            const float rx = refp[rbase + 0];
            const float ry = refp[rbase + 1];
            const float x  = (rx + ox) * Sf - 0.5f;
            const float y  = (ry + oy) * Sf - 0.5f;
            const float x0 = floorf(x), y0 = floorf(y);
            #pragma unroll
            for (int k = 0; k < 4; ++k) {
                const float cx = x0 + (float)(k & 1);
                const float cy = y0 + (float)(k >> 1);
                const float wgt = (1.0f - fabsf(x - cx)) * (1.0f - fabsf(y - cy));
                const bool ok = (cx >= 0.0f) & (cx < Sf) & (cy >= 0.0f) & (cy < Sf);
                const int xi = (int)fminf(fmaxf(cx, 0.0f), Sf - 1.0f);
                const int yi = (int)fminf(fmaxf(cy, 0.0f), Sf - 1.0f);
                cb[k] = ((cbase + yi * S + xi) << 9) + hoff;   // bytes
                const float cw = ok ? wgt * aw : 0.0f;
                const uint_t hw = (uint_t)f2h(cw);
                cwp[k] = (hw << 16) | hw;                      // f16 dup
            }
        }

        // ---- exchange byte offsets for all 4 groups ----
        int b[4][4];
        #pragma unroll
        for (int j = 0; j < 4; ++j) {
            const int src = srcbase + j;
            b[j][0] = __shfl(cb[0], src);
            b[j][1] = __shfl(cb[1], src);
            b[j][2] = __shfl(cb[2], src);
            b[j][3] = __shfl(cb[3], src);
        }

        // ---- depth-2 pipelined gather: group j+1 in flight during j ----
        uint_t acch[4] = {0u, 0u, 0u, 0u};   // packed f16x2, 8 channels
        uint4 v0 = *(const uint4*)(vpb + (b[0][0] + goff));
        uint4 v1 = *(const uint4*)(vpb + (b[0][1] + goff));
        uint4 v2 = *(const uint4*)(vpb + (b[0][2] + goff));
        uint4 v3 = *(const uint4*)(vpb + (b[0][3] + goff));
        #pragma unroll
        for (int j = 0; j < 4; ++j) {
            uint4 n0 = v0, n1 = v1, n2 = v2, n3 = v3;
            if (j < 3) {
                n0 = *(const uint4*)(vpb + (b[j + 1][0] + goff));
                n1 = *(const uint4*)(vpb + (b[j + 1][1] + goff));
                n2 = *(const uint4*)(vpb + (b[j + 1][2] + goff));
                n3 = *(const uint4*)(vpb + (b[j + 1][3] + goff));
            }
            const int src = srcbase + j;
            const uint_t w0 = (uint_t)__shfl((int)cwp[0], src);
            const uint_t w1 = (uint_t)__shfl((int)cwp[1], src);
            const uint_t w2 = (uint_t)__shfl((int)cwp[2], src);
            const uint_t w3 = (uint_t)__shfl((int)cwp[3], src);
            pk_fma8(acch, w0, v0);
            pk_fma8(acch, w1, v1);
            pk_fma8(acch, w2, v2);
            pk_fma8(acch, w3, v3);
            v0 = n0; v1 = n1; v2 = n2; v3 = n3;
        }

        // ---- drain packed f16 accumulators to f32 (once per camera) ----
        #pragma unroll
        for (int n = 0; n < 4; ++n) {
            union { uint_t u; f16x2 h; } cvu;
            cvu.u = acch[n];
            acc[2 * n]     += (float)cvu.h.x;
            acc[2 * n + 1] += (float)cvu.h.y;
        }
    }

    // ---- cross-slice reduction: shfl_xor tree over slice bits (4/8/16) ----
    #pragma unroll
    for (int n = 0; n < 8; ++n) {
        acc[n] += __shfl_xor(acc[n], 4);
        acc[n] += __shfl_xor(acc[n], 8);
        acc[n] += __shfl_xor(acc[n], 16);
    }

    // ---- slot write: slice==0 lanes pack 8 channels -> one 16B store ----
    if (slice == 0) {
        const float inv = 1.0f / fmaxf(cnt, 1.0f);
        uint4 r;
        asm("v_cvt_pk_bf16_f32 %0, %1, %2"
            : "=v"(r.x) : "v"(acc[0] * inv), "v"(acc[1] * inv));
        asm("v_cvt_pk_bf16_f32 %0, %1, %2"
            : "=v"(r.y) : "v"(acc[2] * inv), "v"(acc[3] * inv));
        asm("v_cvt_pk_bf16_f32 %0, %1, %2"
            : "=v"(r.z) : "v"(acc[4] * inv), "v"(acc[5] * inv));
        asm("v_cvt_pk_bf16_f32 %0, %1, %2"
            : "=v"(r.w) : "v"(acc[6] * inv), "v"(acc[7] * inv));
        *(uint4*)(&qkcat[(size_t)q * 768 + 512 + h * 32 + g * 8]) = r;
    }
}

// ---------------------------------------------------------------------------
extern "C" void kernel_launch(void* const* d_in, const int* in_sizes, int n_in,
                              void* d_out, int out_size, void* d_ws, size_t ws_size,
                              hipStream_t stream) {
    const float* query   = (const float*)d_in[0];
    // d_in[1] = key : unused by the deformable-attention math
    const float* value   = (const float*)d_in[2];   // (6,5440,1,256) -> (32640,256)
    const float* refp    = (const float*)d_in[3];
    const int*   vox     = (const int*)d_in[4];
    // d_in[5] spatial_shapes, d_in[6] level_start_index : compile-time constants
    const float* value_W = (const float*)d_in[7];
    const float* value_b = (const float*)d_in[8];
    const float* off_W   = (const float*)d_in[9];
    const float* off_b   = (const float*)d_in[10];
    const float* attw_W  = (const float*)d_in[11];
    const float* attw_b  = (const float*)d_in[12];
    const float* out_W   = (const float*)d_in[13];
    const float* out_b   = (const float*)d_in[14];
    float* out = (float*)d_out;

    // ws layout (bytes):
    //   [0,        16711680)  vproj f16 [32640][256]
    //   [16711680, 32071680)  qkcat bf16 [10000][768] (slots in cols 512..768)
    //   [32071680, 32727040)  value_Wt | out_Wt | qk_Wt  bf16
    char* ws = (char*)d_ws;
    ushort_t* vproj    = (ushort_t*)ws;
    ushort_t* qkcat    = (ushort_t*)(ws + 16711680);
    ushort_t* value_Wt = (ushort_t*)(ws + 32071680);
    ushort_t* out_Wt   = (ushort_t*)(ws + 32071680 + 131072);
    ushort_t* qk_Wt    = (ushort_t*)(ws + 32071680 + 262144);

    // 1. weight transpose+convert -> Wt[n][k] bf16
    prep_w<<<dim3(8, 16, 4), 256, 0, stream>>>(
        value_W, out_W, off_W, attw_W, value_Wt, out_Wt, qk_Wt);
    // 2. value projection (f16 out)
    gemm_v_k<<<510, 256, 0, stream>>>(value, value_Wt, value_b, vproj);
    // 3. offset/attw projection (bf16 out)
    gemm_qk_k<<<474, 256, 0, stream>>>(query, qk_Wt, off_b, attw_b, qkcat);
    // 4-7. deformable sampling, query-range quarters (zero duplication)
    sample_k<<<dim3(2500, 2), 128, 0, stream>>>(qkcat, refp, vox, vproj, 0);
    sample_k<<<dim3(2500, 2), 128, 0, stream>>>(qkcat, refp, vox, vproj, 2500);
    sample_k<<<dim3(2500, 2), 128, 0, stream>>>(qkcat, refp, vox, vproj, 5000);
    sample_k<<<dim3(2500, 2), 128, 0, stream>>>(qkcat, refp, vox, vproj, 7500);
    // 8. output projection + residual, f32 out
    gemm_out_k<<<dim3(79, 2), 256, 0, stream>>>(qkcat + 512, out_Wt, out_b,
                                                query, out);
}

// Round 10
// 305.141 us; speedup vs baseline: 1.1852x; 1.1852x over previous
//
#include <hip/hip_runtime.h>

// ---------------------------------------------------------------------------
// SpatialSatCrossAttention (MS deformable attention, 6 cams, 10000 queries)
// R17: instrumentation (R15) showed tail = 3 GEMMs ~35-48us each (sum ~145us),
//     3x above roofline. Cause: 128x128 tiles -> 510/474/158 blocks = only
//     2 blocks/CU (2 waves/SIMD) -> barrier/latency stalls exposed.
//     Fix: 64x128 tiles (24KB LDS, 32-VGPR acc) -> 1020+942=1962 / 314 blocks
//     (~6 blocks/CU, 6 waves/SIMD). sample_k reverted to R12 single dispatch
//     (150.9us proven; the 4-way split cost 45us).
// Launches (4):
//   1. prep_w    : weight mats -> Wt[n][k] bf16
//   2. gemm_vqk  : vproj = value @ value_W + b (f16); qkcat = query @ W (bf16)
//   3. sample_k  : deformable bilinear sampling -> slots in qkcat[:,512:768]
//   4. gemm_out  : out = slots @ out_W + out_b + query (f32 d_out)
// GEMM body: 64x128 tile, 4 waves (2x2, 32x64 each), 2x4 mfma 16x16x32 bf16,
// BK=32, double-buffered LDS + register prefetch.
// ---------------------------------------------------------------------------

typedef unsigned short ushort_t;
typedef unsigned int uint_t;
typedef __attribute__((ext_vector_type(8))) short bf16x8;
typedef __attribute__((ext_vector_type(4))) float f32x4;
typedef __attribute__((ext_vector_type(2))) _Float16 f16x2;

__device__ __forceinline__ float bf2f(ushort_t u) {
    return __uint_as_float(((uint_t)u) << 16);
}
__device__ __forceinline__ ushort_t f2bf(float f) {
    uint_t i = __float_as_uint(f);
    uint_t r = i + 0x7fffu + ((i >> 16) & 1u);   // round-to-nearest-even
    return (ushort_t)(r >> 16);
}
// 8x f32 -> 8x bf16 via v_cvt_pk_bf16_f32 (RNE)
__device__ __forceinline__ bf16x8 pack8(float4 v0, float4 v1) {
    union { uint_t u[4]; bf16x8 v; } r;
    asm("v_cvt_pk_bf16_f32 %0, %1, %2" : "=v"(r.u[0]) : "v"(v0.x), "v"(v0.y));
    asm("v_cvt_pk_bf16_f32 %0, %1, %2" : "=v"(r.u[1]) : "v"(v0.z), "v"(v0.w));
    asm("v_cvt_pk_bf16_f32 %0, %1, %2" : "=v"(r.u[2]) : "v"(v1.x), "v"(v1.y));
    asm("v_cvt_pk_bf16_f32 %0, %1, %2" : "=v"(r.u[3]) : "v"(v1.z), "v"(v1.w));
    return r.v;
}
__device__ __forceinline__ ushort_t f2h(float f) {
    union { _Float16 h; ushort_t u; } cv;
    cv.h = (_Float16)f;
    return cv.u;
}

// acch[0..3] (packed f16x2, 8 channels) += wp(f16x2 dup) * f16x8(v)
__device__ __forceinline__ void pk_fma8(uint_t* a, uint_t wp, const uint4& v) {
    asm("v_pk_fma_f16 %0, %1, %2, %0" : "+v"(a[0]) : "v"(wp), "v"(v.x));
    asm("v_pk_fma_f16 %0, %1, %2, %0" : "+v"(a[1]) : "v"(wp), "v"(v.y));
    asm("v_pk_fma_f16 %0, %1, %2, %0" : "+v"(a[2]) : "v"(wp), "v"(v.z));
    asm("v_pk_fma_f16 %0, %1, %2, %0" : "+v"(a[3]) : "v"(wp), "v"(v.w));
}

// ---------------------------------------------------------------------------
// prep_w: weight transpose+convert only. W[k][N] f32 -> T[n][256] bf16.
// grid (8,16,4): z=0 value_W, z=1 out_W, z=2 off_W(512), z=3 attw_W.
// ---------------------------------------------------------------------------
__global__ __launch_bounds__(256) void prep_w(
    const float* __restrict__ Wv, const float* __restrict__ Wo,
    const float* __restrict__ Wf, const float* __restrict__ Wa,
    ushort_t* __restrict__ Tv, ushort_t* __restrict__ To,
    ushort_t* __restrict__ Tqk) {
    const int z = blockIdx.z;
    const float* W;
    ushort_t* T;
    int N;
    if (z == 0)      { W = Wv; T = Tv;              N = 256; }
    else if (z == 1) { W = Wo; T = To;              N = 256; }
    else if (z == 2) { W = Wf; T = Tqk;             N = 512; }
    else             { W = Wa; T = Tqk + 512 * 256; N = 256; }
    const int n0 = blockIdx.y * 32;
    if (n0 >= N) return;
    const int k0 = blockIdx.x * 32;

    __shared__ float tile[32][33];
    const int tx = threadIdx.x & 31;
    const int ty = threadIdx.x >> 5;   // 0..7
    #pragma unroll
    for (int r = 0; r < 4; ++r) {
        const int k = ty + r * 8;
        tile[k][tx] = W[(size_t)(k0 + k) * N + n0 + tx];
    }
    __syncthreads();
    #pragma unroll
    for (int r = 0; r < 4; ++r) {
        const int n = ty + r * 8;
        T[(size_t)(n0 + n) * 256 + k0 + tx] = f2bf(tile[tx][n]);
    }
}

// ---------------------------------------------------------------------------
// MFMA GEMM body, 64x128 tile: C[M,N] = A[M,256] @ Wt^T + bias (+resid).
// 4 waves in 2x2; each wave computes 32 rows x 64 cols (2x4 fragments).
// AF32: A is f32, converted to bf16 during LDS staging; else A is bf16.
// OUT_MODE: 0 = f32, 1 = bf16, 2 = f16. Astride: A row stride (elements).
// Wt bf16 [N][256]. N multiple of 128. 256 threads. LDS 24KB -> 6 blocks/CU.
// ---------------------------------------------------------------------------
template <bool AF32, int OUT_MODE, bool RESID>
__device__ __forceinline__ void gemm_body(
    ushort_t (*sA)[64][32], ushort_t (*sB)[128][32],
    const void* __restrict__ Av, int Astride, const ushort_t* __restrict__ Wt,
    const float* __restrict__ bias0, const float* __restrict__ bias1, int split,
    const float* __restrict__ resid, void* __restrict__ Cv,
    int M, int N, int bx, int by) {
    const int m0 = bx * 64;
    const int n0 = by * 128;
    const int t    = threadIdx.x;
    const int lane = t & 63;
    const int w    = t >> 6;
    const int wr   = w >> 1, wc = w & 1;   // wave grid 2x2

    const int srow = t >> 2;          // 0..63
    const int skof = (t & 3) * 8;     // 0,8,16,24

    const bool am0 = (m0 + srow) < M;
    const float*    Af0 = (const float*)Av + (size_t)(m0 + srow) * Astride + skof;
    const ushort_t* Ab0 = (const ushort_t*)Av + (size_t)(m0 + srow) * Astride + skof;
    const ushort_t* Bp0 = Wt + (size_t)(n0 + srow) * 256 + skof;
    const ushort_t* Bp1 = Bp0 + (size_t)64 * 256;

    const bf16x8 zz = {0, 0, 0, 0, 0, 0, 0, 0};

    auto loadA = [&](int ko) -> bf16x8 {
        if (!am0) return zz;
        if (AF32) {
            const float4 v0 = *(const float4*)(Af0 + ko);
            const float4 v1 = *(const float4*)(Af0 + ko + 4);
            return pack8(v0, v1);
        }
        return *(const bf16x8*)(Ab0 + ko);
    };

    f32x4 acc[2][4];
    #pragma unroll
    for (int i = 0; i < 2; ++i)
        #pragma unroll
        for (int j = 0; j < 4; ++j)
            acc[i][j] = (f32x4){0.f, 0.f, 0.f, 0.f};

    // prologue: tile 0 -> LDS[0]
    {
        const bf16x8 a0 = loadA(0);
        const bf16x8 b0 = *(const bf16x8*)(Bp0);
        const bf16x8 b1 = *(const bf16x8*)(Bp1);
        *(bf16x8*)(&sA[0][srow][skof])      = a0;
        *(bf16x8*)(&sB[0][srow][skof])      = b0;
        *(bf16x8*)(&sB[0][64 + srow][skof]) = b1;
    }
    __syncthreads();

    const int rl = lane & 15;
    const int kq = (lane >> 4) * 8;

    for (int k = 0; k < 8; ++k) {
        const int buf = k & 1;

        bf16x8 na0 = zz, nb0 = zz, nb1 = zz;
        if (k < 7) {
            const int ko = (k + 1) * 32;
            na0 = loadA(ko);
            nb0 = *(const bf16x8*)(Bp0 + ko);
            nb1 = *(const bf16x8*)(Bp1 + ko);
        }

        bf16x8 af[2], bfr[4];
        #pragma unroll
        for (int i = 0; i < 2; ++i)
            af[i] = *(const bf16x8*)(&sA[buf][wr * 32 + i * 16 + rl][kq]);
        #pragma unroll
        for (int j = 0; j < 4; ++j)
            bfr[j] = *(const bf16x8*)(&sB[buf][wc * 64 + j * 16 + rl][kq]);
        #pragma unroll
        for (int i = 0; i < 2; ++i)
            #pragma unroll
            for (int j = 0; j < 4; ++j)
                acc[i][j] = __builtin_amdgcn_mfma_f32_16x16x32_bf16(
                    af[i], bfr[j], acc[i][j], 0, 0, 0);

        if (k < 7) {
            __syncthreads();
            *(bf16x8*)(&sA[buf ^ 1][srow][skof])      = na0;
            *(bf16x8*)(&sB[buf ^ 1][srow][skof])      = nb0;
            *(bf16x8*)(&sB[buf ^ 1][64 + srow][skof]) = nb1;
            __syncthreads();
        }
    }

    // --- epilogue: C/D layout col=lane&15, row=(lane>>4)*4+reg (m89) ---
    const int col_l = lane & 15;
    const int rq    = (lane >> 4) * 4;
    #pragma unroll
    for (int j = 0; j < 4; ++j) {
        const int gn = n0 + wc * 64 + j * 16 + col_l;
        const float bj = (gn < split) ? bias0[gn] : bias1[gn - split];
        #pragma unroll
        for (int i = 0; i < 2; ++i) {
            #pragma unroll
            for (int r = 0; r < 4; ++r) {
                const int gm = m0 + wr * 32 + i * 16 + rq + r;
                if (gm >= M) continue;
                float v = acc[i][j][r] + bj;
                if (RESID) v += resid[(size_t)gm * N + gn];
                if (OUT_MODE == 1)
                    ((ushort_t*)Cv)[(size_t)gm * N + gn] = f2bf(v);
                else if (OUT_MODE == 2)
                    ((ushort_t*)Cv)[(size_t)gm * N + gn] = f2h(v);
                else
                    ((float*)Cv)[(size_t)gm * N + gn] = v;
            }
        }
    }
}

// Fused independent GEMMs: blocks [0,1020) -> vproj (510m x 2n, f16 out),
//                          [1020,1962) -> qkcat (157m x 6n, bf16 out).
__global__ __launch_bounds__(256) void gemm_vqk(
    const float* __restrict__ value, const ushort_t* __restrict__ value_Wt,
    const float* __restrict__ value_b, ushort_t* __restrict__ vproj,
    const float* __restrict__ query, const ushort_t* __restrict__ qk_Wt,
    const float* __restrict__ off_b, const float* __restrict__ attw_b,
    ushort_t* __restrict__ qkcat) {
    __shared__ ushort_t sA[2][64][32];
    __shared__ ushort_t sB[2][128][32];
    int b = blockIdx.x;
    if (b < 1020) {
        gemm_body<true, 2, false>(sA, sB, value, 256, value_Wt, value_b,
                                  value_b, 256, nullptr, (void*)vproj,
                                  32640, 256, b >> 1, b & 1);
    } else {
        b -= 1020;
        gemm_body<true, 1, false>(sA, sB, query, 256, qk_Wt, off_b, attw_b,
                                  512, nullptr, (void*)qkcat, 10000, 768,
                                  b / 6, b % 6);
    }
}

__global__ __launch_bounds__(256) void gemm_out_k(
    const ushort_t* __restrict__ slots,   // = qkcat + 512, row stride 768
    const ushort_t* __restrict__ out_Wt,
    const float* __restrict__ out_b, const float* __restrict__ query,
    float* __restrict__ out) {
    __shared__ ushort_t sA[2][64][32];
    __shared__ ushort_t sB[2][128][32];
    const int b = blockIdx.x;
    gemm_body<false, 0, true>(sA, sB, slots, 768, out_Wt, out_b, out_b, 256,
                              query, (void*)out, 10000, 256, b >> 1, b & 1);
}

// ---------------------------------------------------------------------------
// Deformable sampling (R12 structure, proven 150.9us). grid (10000, 2),
// 128 thr (4 heads, hb = blockIdx.y*4). Barrier-free, LDS-free; slice
// reduction via shfl_xor tree; slots packed to one 16B store per writer
// lane into qkcat[:,512:768).
// ---------------------------------------------------------------------------
__global__ __launch_bounds__(128) void sample_k(
    ushort_t* __restrict__ qkcat,        // bf16 [10000, 768]
    const float* __restrict__ refp,      // f32 [6,1,10000,4,2]
    const int* __restrict__ vox,         // int32 [6,1,10000,4]
    const ushort_t* __restrict__ vproj) {// f16 [6*5440, 256]
    const int q    = blockIdx.x;
    const int hb   = blockIdx.y << 2;    // head base: 0 or 4
    const int tid  = threadIdx.x;        // 0..127
    const int lane = tid & 63;
    const int h    = hb + (tid >> 5);    // this thread's head
    const int lp   = tid & 31;           // setup role: (lvl,p)
    const int slice = (tid >> 2) & 7;    // gather role
    const int g     = tid & 3;           // gather role: channels g*8..g*8+7

    // ---- validity: lanes 0..5 load their cam's vox row, broadcast ----
    int mm = 0;
    if (lane < 6) {
        const uint4 vm = *(const uint4*)(vox + ((lane * 10000 + q) << 2));
        mm = (int)(vm.x | vm.y | vm.z | vm.w);
    }
    float sv[6];
    #pragma unroll
    for (int c = 0; c < 6; ++c) sv[c] = __shfl(mm, c) ? 1.0f : 0.0f;
    const float cnt = sv[0] + sv[1] + sv[2] + sv[3] + sv[4] + sv[5];

    // ---- softmax over 32 (lvl,p) entries within this head ----
    const float a = bf2f(qkcat[(size_t)q * 768 + 512 + h * 32 + lp]);
    float mx = a;
    #pragma unroll
    for (int o = 16; o >= 1; o >>= 1) mx = fmaxf(mx, __shfl_xor(mx, o));
    const float e = __expf(a - mx);
    float se = e;
    #pragma unroll
    for (int o = 16; o >= 1; o >>= 1) se += __shfl_xor(se, o);
    const float aw = e / se;

    // ---- camera-independent part of this thread's sample location ----
    const int lvl = lp >> 3;
    const int p   = lp & 7;
    const int dd  = p & 3;
    const int   Sarr[4]   = {64, 32, 16, 8};
    const int   Lstart[4] = {0, 4096, 5120, 5376};
    const int   S  = Sarr[lvl];
    const float Sf = (float)S;
    const int   lstart = Lstart[lvl];
    const int   hoff   = h << 6;     // head byte offset within a row (32ch*2B)
    const float ox = bf2f(qkcat[(size_t)q * 768 + h * 64 + lvl * 16 + p * 2 + 0]) / Sf;
    const float oy = bf2f(qkcat[(size_t)q * 768 + h * 64 + lvl * 16 + p * 2 + 1]) / Sf;

    float acc[8] = {0.f, 0.f, 0.f, 0.f, 0.f, 0.f, 0.f, 0.f};
    const char* vpb = (const char*)vproj;
    const int goff = g << 4;             // 4 lanes x 16B within 64B chunk
    const int srcbase = (lane & 32) + slice * 4;

    for (int c = 0; c < 6; ++c) {
        if (sv[c] == 0.0f) continue;     // block-uniform branch

        // ---- setup: corner BYTE offsets + packed-f16 weights ----
        int    cb[4];
        uint_t cwp[4];
        {
            const int cbase = c * 5440 + lstart;
            const int rbase = ((c * 10000 + q) * 4 + dd) * 2;
            const float rx = refp[rbase + 0];
            const float ry = refp[rbase + 1];
            const float x  = (rx + ox) * Sf - 0.5f;
            const float y  = (ry + oy) * Sf - 0.5f;
            const float x0 = floorf(x), y0 = floorf(y);
            #pragma unroll
            for (int k = 0; k < 4; ++k) {
                const float cx = x0 + (float)(k & 1);
                const float cy = y0 + (float)(k >> 1);
                const float wgt = (1.0f - fabsf(x - cx)) * (1.0f - fabsf(y - cy));
                const bool ok = (cx >= 0.0f) & (cx < Sf) & (cy >= 0.0f) & (cy < Sf);
                const int xi = (int)fminf(fmaxf(cx, 0.0f), Sf - 1.0f);
                const int yi = (int)fminf(fmaxf(cy, 0.0f), Sf - 1.0f);
                cb[k] = ((cbase + yi * S + xi) << 9) + hoff;   // bytes
                const float cw = ok ? wgt * aw : 0.0f;
                const uint_t hw = (uint_t)f2h(cw);
                cwp[k] = (hw << 16) | hw;                      // f16 dup
            }
        }

        // ---- exchange byte offsets for all 4 groups ----
        int b[4][4];
        #pragma unroll
        for (int j = 0; j < 4; ++j) {
            const int src = srcbase + j;
            b[j][0] = __shfl(cb[0], src);
            b[j][1] = __shfl(cb[1], src);
            b[j][2] = __shfl(cb[2], src);
            b[j][3] = __shfl(cb[3], src);
        }

        // ---- depth-2 pipelined gather: group j+1 in flight during j ----
        uint_t acch[4] = {0u, 0u, 0u, 0u};   // packed f16x2, 8 channels
        uint4 v0 = *(const uint4*)(vpb + (b[0][0] + goff));
        uint4 v1 = *(const uint4*)(vpb + (b[0][1] + goff));
        uint4 v2 = *(const uint4*)(vpb + (b[0][2] + goff));
        uint4 v3 = *(const uint4*)(vpb + (b[0][3] + goff));
        #pragma unroll
        for (int j = 0; j < 4; ++j) {
            uint4 n0 = v0, n1 = v1, n2 = v2, n3 = v3;
            if (j < 3) {
                n0 = *(const uint4*)(vpb + (b[j + 1][0] + goff));
                n1 = *(const uint4*)(vpb + (b[j + 1][1] + goff));
                n2 = *(const uint4*)(vpb + (b[j + 1][2] + goff));
                n3 = *(const uint4*)(vpb + (b[j + 1][3] + goff));
            }
            const int src = srcbase + j;
            const uint_t w0 = (uint_t)__shfl((int)cwp[0], src);
            const uint_t w1 = (uint_t)__shfl((int)cwp[1], src);
            const uint_t w2 = (uint_t)__shfl((int)cwp[2], src);
            const uint_t w3 = (uint_t)__shfl((int)cwp[3], src);
            pk_fma8(acch, w0, v0);
            pk_fma8(acch, w1, v1);
            pk_fma8(acch, w2, v2);
            pk_fma8(acch, w3, v3);
            v0 = n0; v1 = n1; v2 = n2; v3 = n3;
        }

        // ---- drain packed f16 accumulators to f32 (once per camera) ----
        #pragma unroll
        for (int n = 0; n < 4; ++n) {
            union { uint_t u; f16x2 h; } cvu;
            cvu.u = acch[n];
            acc[2 * n]     += (float)cvu.h.x;
            acc[2 * n + 1] += (float)cvu.h.y;
        }
    }

    // ---- cross-slice reduction: shfl_xor tree over slice bits (4/8/16) ----
    #pragma unroll
    for (int n = 0; n < 8; ++n) {
        acc[n] += __shfl_xor(acc[n], 4);
        acc[n] += __shfl_xor(acc[n], 8);
        acc[n] += __shfl_xor(acc[n], 16);
    }

    // ---- slot write: slice==0 lanes pack 8 channels -> one 16B store ----
    if (slice == 0) {
        const float inv = 1.0f / fmaxf(cnt, 1.0f);
        uint4 r;
        asm("v_cvt_pk_bf16_f32 %0, %1, %2"
            : "=v"(r.x) : "v"(acc[0] * inv), "v"(acc[1] * inv));
        asm("v_cvt_pk_bf16_f32 %0, %1, %2"
            : "=v"(r.y) : "v"(acc[2] * inv), "v"(acc[3] * inv));
        asm("v_cvt_pk_bf16_f32 %0, %1, %2"
            : "=v"(r.z) : "v"(acc[4] * inv), "v"(acc[5] * inv));
        asm("v_cvt_pk_bf16_f32 %0, %1, %2"
            : "=v"(r.w) : "v"(acc[6] * inv), "v"(acc[7] * inv));
        *(uint4*)(&qkcat[(size_t)q * 768 + 512 + h * 32 + g * 8]) = r;
    }
}

// ---------------------------------------------------------------------------
extern "C" void kernel_launch(void* const* d_in, const int* in_sizes, int n_in,
                              void* d_out, int out_size, void* d_ws, size_t ws_size,
                              hipStream_t stream) {
    const float* query   = (const float*)d_in[0];
    // d_in[1] = key : unused by the deformable-attention math
    const float* value   = (const float*)d_in[2];   // (6,5440,1,256) -> (32640,256)
    const float* refp    = (const float*)d_in[3];
    const int*   vox     = (const int*)d_in[4];
    // d_in[5] spatial_shapes, d_in[6] level_start_index : compile-time constants
    const float* value_W = (const float*)d_in[7];
    const float* value_b = (const float*)d_in[8];
    const float* off_W   = (const float*)d_in[9];
    const float* off_b   = (const float*)d_in[10];
    const float* attw_W  = (const float*)d_in[11];
    const float* attw_b  = (const float*)d_in[12];
    const float* out_W   = (const float*)d_in[13];
    const float* out_b   = (const float*)d_in[14];
    float* out = (float*)d_out;

    // ws layout (bytes):
    //   [0,        16711680)  vproj f16 [32640][256]
    //   [16711680, 32071680)  qkcat bf16 [10000][768] (slots in cols 512..768)
    //   [32071680, 32727040)  value_Wt | out_Wt | qk_Wt  bf16
    char* ws = (char*)d_ws;
    ushort_t* vproj    = (ushort_t*)ws;
    ushort_t* qkcat    = (ushort_t*)(ws + 16711680);
    ushort_t* value_Wt = (ushort_t*)(ws + 32071680);
    ushort_t* out_Wt   = (ushort_t*)(ws + 32071680 + 131072);
    ushort_t* qk_Wt    = (ushort_t*)(ws + 32071680 + 262144);

    // 1. weight transpose+convert -> Wt[n][k] bf16
    prep_w<<<dim3(8, 16, 4), 256, 0, stream>>>(
        value_W, out_W, off_W, attw_W, value_Wt, out_Wt, qk_Wt);
    // 2. fused value-proj (f16 out) + offset/attw-proj (bf16 out), 64x128 tiles
    gemm_vqk<<<1962, 256, 0, stream>>>(value, value_Wt, value_b, vproj,
                                       query, qk_Wt, off_b, attw_b, qkcat);
    // 3. deformable sampling + softmax + camera mask/count -> slots in qkcat
    sample_k<<<dim3(10000, 2), 128, 0, stream>>>(qkcat, refp, vox, vproj);
    // 4. output projection + residual, f32 out
    gemm_out_k<<<314, 256, 0, stream>>>(qkcat + 512, out_Wt, out_b,
                                        query, out);
}

// Round 11
// 301.537 us; speedup vs baseline: 1.1994x; 1.0120x over previous
//
#include <hip/hip_runtime.h>

// ---------------------------------------------------------------------------
// SpatialSatCrossAttention (MS deformable attention, 6 cams, 10000 queries)
// R18: R17 (64x128 tiles, 6 blk/CU) cut tail 175->154us. Remaining stall is
//     in-block: (1) 2 barriers/K-iter where 1 suffices (alternating dbuf:
//     reads of buf^1 at iter k-1 and write at iter k are separated by the
//     k-1 end barrier); (2) A-loads (HBM ~900cyc) issued with only ~1 iter
//     of distance, and AF32 pack8 forced the vmcnt wait at issue. Fix:
//     single barrier per iter (after write) + depth-3 A pipeline (raw f32
//     generations for k+1/k+2 in regs, k+3 in flight, convert at write).
//     B stays depth-2 (L2-hot). sample_k = R12 proven (150.5us) untouched.
// Launches (4):
//   1. prep_w    : weight mats -> Wt[n][k] bf16
//   2. gemm_vqk  : vproj = value @ value_W + b (f16); qkcat = query @ W (bf16)
//   3. sample_k  : deformable bilinear sampling -> slots in qkcat[:,512:768]
//   4. gemm_out  : out = slots @ out_W + out_b + query (f32 d_out)
// GEMM body: 64x128 tile, 4 waves (2x2, 32x64 each), 2x4 mfma 16x16x32 bf16,
// BK=32, double-buffered LDS, 1 barrier/iter, depth-3 A prefetch.
// ---------------------------------------------------------------------------

typedef unsigned short ushort_t;
typedef unsigned int uint_t;
typedef __attribute__((ext_vector_type(8))) short bf16x8;
typedef __attribute__((ext_vector_type(4))) float f32x4;
typedef __attribute__((ext_vector_type(2))) _Float16 f16x2;

__device__ __forceinline__ float bf2f(ushort_t u) {
    return __uint_as_float(((uint_t)u) << 16);
}
__device__ __forceinline__ ushort_t f2bf(float f) {
    uint_t i = __float_as_uint(f);
    uint_t r = i + 0x7fffu + ((i >> 16) & 1u);   // round-to-nearest-even
    return (ushort_t)(r >> 16);
}
// 8x f32 -> 8x bf16 via v_cvt_pk_bf16_f32 (RNE)
__device__ __forceinline__ bf16x8 pack8(float4 v0, float4 v1) {
    union { uint_t u[4]; bf16x8 v; } r;
    asm("v_cvt_pk_bf16_f32 %0, %1, %2" : "=v"(r.u[0]) : "v"(v0.x), "v"(v0.y));
    asm("v_cvt_pk_bf16_f32 %0, %1, %2" : "=v"(r.u[1]) : "v"(v0.z), "v"(v0.w));
    asm("v_cvt_pk_bf16_f32 %0, %1, %2" : "=v"(r.u[2]) : "v"(v1.x), "v"(v1.y));
    asm("v_cvt_pk_bf16_f32 %0, %1, %2" : "=v"(r.u[3]) : "v"(v1.z), "v"(v1.w));
    return r.v;
}
__device__ __forceinline__ ushort_t f2h(float f) {
    union { _Float16 h; ushort_t u; } cv;
    cv.h = (_Float16)f;
    return cv.u;
}

// acch[0..3] (packed f16x2, 8 channels) += wp(f16x2 dup) * f16x8(v)
__device__ __forceinline__ void pk_fma8(uint_t* a, uint_t wp, const uint4& v) {
    asm("v_pk_fma_f16 %0, %1, %2, %0" : "+v"(a[0]) : "v"(wp), "v"(v.x));
    asm("v_pk_fma_f16 %0, %1, %2, %0" : "+v"(a[1]) : "v"(wp), "v"(v.y));
    asm("v_pk_fma_f16 %0, %1, %2, %0" : "+v"(a[2]) : "v"(wp), "v"(v.z));
    asm("v_pk_fma_f16 %0, %1, %2, %0" : "+v"(a[3]) : "v"(wp), "v"(v.w));
}

// ---------------------------------------------------------------------------
// prep_w: weight transpose+convert only. W[k][N] f32 -> T[n][256] bf16.
// grid (8,16,4): z=0 value_W, z=1 out_W, z=2 off_W(512), z=3 attw_W.
// ---------------------------------------------------------------------------
__global__ __launch_bounds__(256) void prep_w(
    const float* __restrict__ Wv, const float* __restrict__ Wo,
    const float* __restrict__ Wf, const float* __restrict__ Wa,
    ushort_t* __restrict__ Tv, ushort_t* __restrict__ To,
    ushort_t* __restrict__ Tqk) {
    const int z = blockIdx.z;
    const float* W;
    ushort_t* T;
    int N;
    if (z == 0)      { W = Wv; T = Tv;              N = 256; }
    else if (z == 1) { W = Wo; T = To;              N = 256; }
    else if (z == 2) { W = Wf; T = Tqk;             N = 512; }
    else             { W = Wa; T = Tqk + 512 * 256; N = 256; }
    const int n0 = blockIdx.y * 32;
    if (n0 >= N) return;
    const int k0 = blockIdx.x * 32;

    __shared__ float tile[32][33];
    const int tx = threadIdx.x & 31;
    const int ty = threadIdx.x >> 5;   // 0..7
    #pragma unroll
    for (int r = 0; r < 4; ++r) {
        const int k = ty + r * 8;
        tile[k][tx] = W[(size_t)(k0 + k) * N + n0 + tx];
    }
    __syncthreads();
    #pragma unroll
    for (int r = 0; r < 4; ++r) {
        const int n = ty + r * 8;
        T[(size_t)(n0 + n) * 256 + k0 + tx] = f2bf(tile[tx][n]);
    }
}

// ---------------------------------------------------------------------------
// MFMA GEMM body, 64x128 tile: C[M,N] = A[M,256] @ Wt^T + bias (+resid).
// 4 waves in 2x2; each wave computes 32 rows x 64 cols (2x4 fragments).
// Single barrier per K-iter (after LDS write); depth-3 A prefetch (raw f32
// held 2 generations, converted at write time); depth-2 B prefetch.
// AF32: A is f32. OUT_MODE: 0=f32, 1=bf16, 2=f16. Astride: A row stride.
// Wt bf16 [N][256]. 256 threads. LDS 24KB.
// ---------------------------------------------------------------------------
template <bool AF32, int OUT_MODE, bool RESID>
__device__ __forceinline__ void gemm_body(
    ushort_t (*sA)[64][32], ushort_t (*sB)[128][32],
    const void* __restrict__ Av, int Astride, const ushort_t* __restrict__ Wt,
    const float* __restrict__ bias0, const float* __restrict__ bias1, int split,
    const float* __restrict__ resid, void* __restrict__ Cv,
    int M, int N, int bx, int by) {
    const int m0 = bx * 64;
    const int n0 = by * 128;
    const int t    = threadIdx.x;
    const int lane = t & 63;
    const int w    = t >> 6;
    const int wr   = w >> 1, wc = w & 1;   // wave grid 2x2

    const int srow = t >> 2;          // 0..63
    const int skof = (t & 3) * 8;     // 0,8,16,24

    const bool am0 = (m0 + srow) < M;
    const float*    Af0 = (const float*)Av + (size_t)(m0 + srow) * Astride + skof;
    const ushort_t* Ab0 = (const ushort_t*)Av + (size_t)(m0 + srow) * Astride + skof;
    const ushort_t* Bp0 = Wt + (size_t)(n0 + srow) * 256 + skof;
    const ushort_t* Bp1 = Bp0 + (size_t)64 * 256;

    const bf16x8 zz = {0, 0, 0, 0, 0, 0, 0, 0};
    const float4 fz = {0.f, 0.f, 0.f, 0.f};

    f32x4 acc[2][4];
    #pragma unroll
    for (int i = 0; i < 2; ++i)
        #pragma unroll
        for (int j = 0; j < 4; ++j)
            acc[i][j] = (f32x4){0.f, 0.f, 0.f, 0.f};

    // A prefetch generations: gen1 = data for k+1, gen2 = data for k+2
    float4 af1a = fz, af1b = fz, af2a = fz, af2b = fz;   // AF32 path
    bf16x8 ab1 = zz, ab2 = zz;                           // bf16 path

    // prologue: k0 -> LDS[0]; issue A loads for k1, k2
    {
        bf16x8 a0;
        if (AF32) {
            float4 v0 = fz, v1 = fz;
            if (am0) { v0 = *(const float4*)(Af0); v1 = *(const float4*)(Af0 + 4); }
            if (am0) {
                af1a = *(const float4*)(Af0 + 32); af1b = *(const float4*)(Af0 + 36);
                af2a = *(const float4*)(Af0 + 64); af2b = *(const float4*)(Af0 + 68);
            }
            a0 = am0 ? pack8(v0, v1) : zz;
        } else {
            a0 = am0 ? *(const bf16x8*)(Ab0) : zz;
            if (am0) {
                ab1 = *(const bf16x8*)(Ab0 + 32);
                ab2 = *(const bf16x8*)(Ab0 + 64);
            }
        }
        const bf16x8 b0 = *(const bf16x8*)(Bp0);
        const bf16x8 b1 = *(const bf16x8*)(Bp1);
        *(bf16x8*)(&sA[0][srow][skof])      = a0;
        *(bf16x8*)(&sB[0][srow][skof])      = b0;
        *(bf16x8*)(&sB[0][64 + srow][skof]) = b1;
    }
    __syncthreads();

    const int rl = lane & 15;
    const int kq = (lane >> 4) * 8;

    #pragma unroll
    for (int k = 0; k < 8; ++k) {
        const int buf = k & 1;

        // issue A loads for k+3 (depth-3)
        float4 nfa = fz, nfb = fz;
        bf16x8 nab = zz;
        if (k < 5 && am0) {
            const int ko = (k + 3) * 32;
            if (AF32) {
                nfa = *(const float4*)(Af0 + ko);
                nfb = *(const float4*)(Af0 + ko + 4);
            } else {
                nab = *(const bf16x8*)(Ab0 + ko);
            }
        }
        // issue B loads for k+1 (depth-2, L2-hot)
        bf16x8 nb0 = zz, nb1 = zz;
        if (k < 7) {
            const int ko = (k + 1) * 32;
            nb0 = *(const bf16x8*)(Bp0 + ko);
            nb1 = *(const bf16x8*)(Bp1 + ko);
        }

        // fragments + MFMA from LDS[buf]
        bf16x8 af[2], bfr[4];
        #pragma unroll
        for (int i = 0; i < 2; ++i)
            af[i] = *(const bf16x8*)(&sA[buf][wr * 32 + i * 16 + rl][kq]);
        #pragma unroll
        for (int j = 0; j < 4; ++j)
            bfr[j] = *(const bf16x8*)(&sB[buf][wc * 64 + j * 16 + rl][kq]);
        #pragma unroll
        for (int i = 0; i < 2; ++i)
            #pragma unroll
            for (int j = 0; j < 4; ++j)
                acc[i][j] = __builtin_amdgcn_mfma_f32_16x16x32_bf16(
                    af[i], bfr[j], acc[i][j], 0, 0, 0);

        if (k < 7) {
            // write k+1 tile to LDS[buf^1]; safe without a pre-barrier:
            // buf^1 was last read at iter k-1, separated by that iter's
            // barrier (compiler drains lgkmcnt before s_barrier).
            const bf16x8 wa = AF32 ? (am0 ? pack8(af1a, af1b) : zz) : ab1;
            *(bf16x8*)(&sA[buf ^ 1][srow][skof])      = wa;
            *(bf16x8*)(&sB[buf ^ 1][srow][skof])      = nb0;
            *(bf16x8*)(&sB[buf ^ 1][64 + srow][skof]) = nb1;
            __syncthreads();
            // rotate A generations
            if (AF32) {
                af1a = af2a; af1b = af2b;
                af2a = nfa;  af2b = nfb;
            } else {
                ab1 = ab2;
                ab2 = nab;
            }
        }
    }

    // --- epilogue: C/D layout col=lane&15, row=(lane>>4)*4+reg (m89) ---
    const int col_l = lane & 15;
    const int rq    = (lane >> 4) * 4;
    #pragma unroll
    for (int j = 0; j < 4; ++j) {
        const int gn = n0 + wc * 64 + j * 16 + col_l;
        const float bj = (gn < split) ? bias0[gn] : bias1[gn - split];
        #pragma unroll
        for (int i = 0; i < 2; ++i) {
            #pragma unroll
            for (int r = 0; r < 4; ++r) {
                const int gm = m0 + wr * 32 + i * 16 + rq + r;
                if (gm >= M) continue;
                float v = acc[i][j][r] + bj;
                if (RESID) v += resid[(size_t)gm * N + gn];
                if (OUT_MODE == 1)
                    ((ushort_t*)Cv)[(size_t)gm * N + gn] = f2bf(v);
                else if (OUT_MODE == 2)
                    ((ushort_t*)Cv)[(size_t)gm * N + gn] = f2h(v);
                else
                    ((float*)Cv)[(size_t)gm * N + gn] = v;
            }
        }
    }
}

// Fused independent GEMMs: blocks [0,1020) -> vproj (510m x 2n, f16 out),
//                          [1020,1962) -> qkcat (157m x 6n, bf16 out).
__global__ __launch_bounds__(256) void gemm_vqk(
    const float* __restrict__ value, const ushort_t* __restrict__ value_Wt,
    const float* __restrict__ value_b, ushort_t* __restrict__ vproj,
    const float* __restrict__ query, const ushort_t* __restrict__ qk_Wt,
    const float* __restrict__ off_b, const float* __restrict__ attw_b,
    ushort_t* __restrict__ qkcat) {
    __shared__ ushort_t sA[2][64][32];
    __shared__ ushort_t sB[2][128][32];
    int b = blockIdx.x;
    if (b < 1020) {
        gemm_body<true, 2, false>(sA, sB, value, 256, value_Wt, value_b,
                                  value_b, 256, nullptr, (void*)vproj,
                                  32640, 256, b >> 1, b & 1);
    } else {
        b -= 1020;
        gemm_body<true, 1, false>(sA, sB, query, 256, qk_Wt, off_b, attw_b,
                                  512, nullptr, (void*)qkcat, 10000, 768,
                                  b / 6, b % 6);
    }
}

__global__ __launch_bounds__(256) void gemm_out_k(
    const ushort_t* __restrict__ slots,   // = qkcat + 512, row stride 768
    const ushort_t* __restrict__ out_Wt,
    const float* __restrict__ out_b, const float* __restrict__ query,
    float* __restrict__ out) {
    __shared__ ushort_t sA[2][64][32];
    __shared__ ushort_t sB[2][128][32];
    const int b = blockIdx.x;
    gemm_body<false, 0, true>(sA, sB, slots, 768, out_Wt, out_b, out_b, 256,
                              query, (void*)out, 10000, 256, b >> 1, b & 1);
}

// ---------------------------------------------------------------------------
// Deformable sampling (R12 structure, proven 150.5us). grid (10000, 2),
// 128 thr (4 heads, hb = blockIdx.y*4). Barrier-free, LDS-free; slice
// reduction via shfl_xor tree; slots packed to one 16B store per writer
// lane into qkcat[:,512:768).
// ---------------------------------------------------------------------------
__global__ __launch_bounds__(128) void sample_k(
    ushort_t* __restrict__ qkcat,        // bf16 [10000, 768]
    const float* __restrict__ refp,      // f32 [6,1,10000,4,2]
    const int* __restrict__ vox,         // int32 [6,1,10000,4]
    const ushort_t* __restrict__ vproj) {// f16 [6*5440, 256]
    const int q    = blockIdx.x;
    const int hb   = blockIdx.y << 2;    // head base: 0 or 4
    const int tid  = threadIdx.x;        // 0..127
    const int lane = tid & 63;
    const int h    = hb + (tid >> 5);    // this thread's head
    const int lp   = tid & 31;           // setup role: (lvl,p)
    const int slice = (tid >> 2) & 7;    // gather role
    const int g     = tid & 3;           // gather role: channels g*8..g*8+7

    // ---- validity: lanes 0..5 load their cam's vox row, broadcast ----
    int mm = 0;
    if (lane < 6) {
        const uint4 vm = *(const uint4*)(vox + ((lane * 10000 + q) << 2));
        mm = (int)(vm.x | vm.y | vm.z | vm.w);
    }
    float sv[6];
    #pragma unroll
    for (int c = 0; c < 6; ++c) sv[c] = __shfl(mm, c) ? 1.0f : 0.0f;
    const float cnt = sv[0] + sv[1] + sv[2] + sv[3] + sv[4] + sv[5];

    // ---- softmax over 32 (lvl,p) entries within this head ----
    const float a = bf2f(qkcat[(size_t)q * 768 + 512 + h * 32 + lp]);
    float mx = a;
    #pragma unroll
    for (int o = 16; o >= 1; o >>= 1) mx = fmaxf(mx, __shfl_xor(mx, o));
    const float e = __expf(a - mx);
    float se = e;
    #pragma unroll
    for (int o = 16; o >= 1; o >>= 1) se += __shfl_xor(se, o);
    const float aw = e / se;

    // ---- camera-independent part of this thread's sample location ----
    const int lvl = lp >> 3;
    const int p   = lp & 7;
    const int dd  = p & 3;
    const int   Sarr[4]   = {64, 32, 16, 8};
    const int   Lstart[4] = {0, 4096, 5120, 5376};
    const int   S  = Sarr[lvl];
    const float Sf = (float)S;
    const int   lstart = Lstart[lvl];
    const int   hoff   = h << 6;     // head byte offset within a row (32ch*2B)
    const float ox = bf2f(qkcat[(size_t)q * 768 + h * 64 + lvl * 16 + p * 2 + 0]) / Sf;
    const float oy = bf2f(qkcat[(size_t)q * 768 + h * 64 + lvl * 16 + p * 2 + 1]) / Sf;

    float acc[8] = {0.f, 0.f, 0.f, 0.f, 0.f, 0.f, 0.f, 0.f};
    const char* vpb = (const char*)vproj;
    const int goff = g << 4;             // 4 lanes x 16B within 64B chunk
    const int srcbase = (lane & 32) + slice * 4;

    for (int c = 0; c < 6; ++c) {
        if (sv[c] == 0.0f) continue;     // block-uniform branch

        // ---- setup: corner BYTE offsets + packed-f16 weights ----
        int    cb[4];
        uint_t cwp[4];
        {
            const int cbase = c * 5440 + lstart;
            const int rbase = ((c * 10000 + q) * 4 + dd) * 2;
            const float rx = refp[rbase + 0];
            const float ry = refp[rbase + 1];
            const float x  = (rx + ox) * Sf - 0.5f;
            const float y  = (ry + oy) * Sf - 0.5f;
            const float x0 = floorf(x), y0 = floorf(y);
            #pragma unroll
            for (int k = 0; k < 4; ++k) {
                const float cx = x0 + (float)(k & 1);
                const float cy = y0 + (float)(k >> 1);
                const float wgt = (1.0f - fabsf(x - cx)) * (1.0f - fabsf(y - cy));
                const bool ok = (cx >= 0.0f) & (cx < Sf) & (cy >= 0.0f) & (cy < Sf);
                const int xi = (int)fminf(fmaxf(cx, 0.0f), Sf - 1.0f);
                const int yi = (int)fminf(fmaxf(cy, 0.0f), Sf - 1.0f);
                cb[k] = ((cbase + yi * S + xi) << 9) + hoff;   // bytes
                const float cw = ok ? wgt * aw : 0.0f;
                const uint_t hw = (uint_t)f2h(cw);
                cwp[k] = (hw << 16) | hw;                      // f16 dup
            }
        }

        // ---- exchange byte offsets for all 4 groups ----
        int b[4][4];
        #pragma unroll
        for (int j = 0; j < 4; ++j) {
            const int src = srcbase + j;
            b[j][0] = __shfl(cb[0], src);
            b[j][1] = __shfl(cb[1], src);
            b[j][2] = __shfl(cb[2], src);
            b[j][3] = __shfl(cb[3], src);
        }

        // ---- depth-2 pipelined gather: group j+1 in flight during j ----
        uint_t acch[4] = {0u, 0u, 0u, 0u};   // packed f16x2, 8 channels
        uint4 v0 = *(const uint4*)(vpb + (b[0][0] + goff));
        uint4 v1 = *(const uint4*)(vpb + (b[0][1] + goff));
        uint4 v2 = *(const uint4*)(vpb + (b[0][2] + goff));
        uint4 v3 = *(const uint4*)(vpb + (b[0][3] + goff));
        #pragma unroll
        for (int j = 0; j < 4; ++j) {
            uint4 n0 = v0, n1 = v1, n2 = v2, n3 = v3;
            if (j < 3) {
                n0 = *(const uint4*)(vpb + (b[j + 1][0] + goff));
                n1 = *(const uint4*)(vpb + (b[j + 1][1] + goff));
                n2 = *(const uint4*)(vpb + (b[j + 1][2] + goff));
                n3 = *(const uint4*)(vpb + (b[j + 1][3] + goff));
            }
            const int src = srcbase + j;
            const uint_t w0 = (uint_t)__shfl((int)cwp[0], src);
            const uint_t w1 = (uint_t)__shfl((int)cwp[1], src);
            const uint_t w2 = (uint_t)__shfl((int)cwp[2], src);
            const uint_t w3 = (uint_t)__shfl((int)cwp[3], src);
            pk_fma8(acch, w0, v0);
            pk_fma8(acch, w1, v1);
            pk_fma8(acch, w2, v2);
            pk_fma8(acch, w3, v3);
            v0 = n0; v1 = n1; v2 = n2; v3 = n3;
        }

        // ---- drain packed f16 accumulators to f32 (once per camera) ----
        #pragma unroll
        for (int n = 0; n < 4; ++n) {
            union { uint_t u; f16x2 h; } cvu;
            cvu.u = acch[n];
            acc[2 * n]     += (float)cvu.h.x;
            acc[2 * n + 1] += (float)cvu.h.y;
        }
    }

    // ---- cross-slice reduction: shfl_xor tree over slice bits (4/8/16) ----
    #pragma unroll
    for (int n = 0; n < 8; ++n) {
        acc[n] += __shfl_xor(acc[n], 4);
        acc[n] += __shfl_xor(acc[n], 8);
        acc[n] += __shfl_xor(acc[n], 16);
    }

    // ---- slot write: slice==0 lanes pack 8 channels -> one 16B store ----
    if (slice == 0) {
        const float inv = 1.0f / fmaxf(cnt, 1.0f);
        uint4 r;
        asm("v_cvt_pk_bf16_f32 %0, %1, %2"
            : "=v"(r.x) : "v"(acc[0] * inv), "v"(acc[1] * inv));
        asm("v_cvt_pk_bf16_f32 %0, %1, %2"
            : "=v"(r.y) : "v"(acc[2] * inv), "v"(acc[3] * inv));
        asm("v_cvt_pk_bf16_f32 %0, %1, %2"
            : "=v"(r.z) : "v"(acc[4] * inv), "v"(acc[5] * inv));
        asm("v_cvt_pk_bf16_f32 %0, %1, %2"
            : "=v"(r.w) : "v"(acc[6] * inv), "v"(acc[7] * inv));
        *(uint4*)(&qkcat[(size_t)q * 768 + 512 + h * 32 + g * 8]) = r;
    }
}

// ---------------------------------------------------------------------------
extern "C" void kernel_launch(void* const* d_in, const int* in_sizes, int n_in,
                              void* d_out, int out_size, void* d_ws, size_t ws_size,
                              hipStream_t stream) {
    const float* query   = (const float*)d_in[0];
    // d_in[1] = key : unused by the deformable-attention math
    const float* value   = (const float*)d_in[2];   // (6,5440,1,256) -> (32640,256)
    const float* refp    = (const float*)d_in[3];
    const int*   vox     = (const int*)d_in[4];
    // d_in[5] spatial_shapes, d_in[6] level_start_index : compile-time constants
    const float* value_W = (const float*)d_in[7];
    const float* value_b = (const float*)d_in[8];
    const float* off_W   = (const float*)d_in[9];
    const float* off_b   = (const float*)d_in[10];
    const float* attw_W  = (const float*)d_in[11];
    const float* attw_b  = (const float*)d_in[12];
    const float* out_W   = (const float*)d_in[13];
    const float* out_b   = (const float*)d_in[14];
    float* out = (float*)d_out;

    // ws layout (bytes):
    //   [0,        16711680)  vproj f16 [32640][256]
    //   [16711680, 32071680)  qkcat bf16 [10000][768] (slots in cols 512..768)
    //   [32071680, 32727040)  value_Wt | out_Wt | qk_Wt  bf16
    char* ws = (char*)d_ws;
    ushort_t* vproj    = (ushort_t*)ws;
    ushort_t* qkcat    = (ushort_t*)(ws + 16711680);
    ushort_t* value_Wt = (ushort_t*)(ws + 32071680);
    ushort_t* out_Wt   = (ushort_t*)(ws + 32071680 + 131072);
    ushort_t* qk_Wt    = (ushort_t*)(ws + 32071680 + 262144);

    // 1. weight transpose+convert -> Wt[n][k] bf16
    prep_w<<<dim3(8, 16, 4), 256, 0, stream>>>(
        value_W, out_W, off_W, attw_W, value_Wt, out_Wt, qk_Wt);
    // 2. fused value-proj (f16 out) + offset/attw-proj (bf16 out), 64x128 tiles
    gemm_vqk<<<1962, 256, 0, stream>>>(value, value_Wt, value_b, vproj,
                                       query, qk_Wt, off_b, attw_b, qkcat);
    // 3. deformable sampling + softmax + camera mask/count -> slots in qkcat
    sample_k<<<dim3(10000, 2), 128, 0, stream>>>(qkcat, refp, vox, vproj);
    // 4. output projection + residual, f32 out
    gemm_out_k<<<314, 256, 0, stream>>>(qkcat + 512, out_Wt, out_b,
                                        query, out);
}

// Round 13
// 301.336 us; speedup vs baseline: 1.2002x; 1.0007x over previous
//
#include <hip/hip_runtime.h>

// ---------------------------------------------------------------------------
// SpatialSatCrossAttention (MS deformable attention, 6 cams, 10000 queries)
// R20 = R19 resubmit (bench failed on container acquisition; same infra error
//     as R15 which passed verbatim on resubmit. Kernel re-audited: uniform
//     barriers, no waitcnt deadlock, wave-uniform global_load_lds dests,
//     bounds-clamped addresses).
// R19: R18's register prefetch was defeated by the compiler's vmcnt(0) drain
//     before every __syncthreads (each K-iter waited the just-issued HBM
//     A-load, ~700-900cyc x 8 iters). Fix = counted-vmcnt + raw s_barrier:
//     B staged via global_load_lds (LDS dest is wave-uniform + lane*16 in
//     this layout), A reg-depth-3 (f32 paths) or global_load_lds (bf16 path),
//     per-wave pre-barrier gate s_waitcnt vmcnt(N) lgkmcnt(0) with N counting
//     only ops newer than the B-stage -> the A HBM stream stays in flight
//     across barriers (AITER pattern: vmcnt never 0 mid-loop where possible).
//     Issue order pinned with sched_barrier(0) (vmcnt retires in order).
//     sample_k untouched (R12, 149.5us = 71% of L2 random-gather ceiling).
// Launches (4):
//   1. prep_w    : weight mats -> Wt[n][k] bf16
//   2. gemm_vqk  : vproj = value @ value_W + b (f16); qkcat = query @ W (bf16)
//   3. sample_k  : deformable bilinear sampling -> slots in qkcat[:,512:768]
//   4. gemm_out  : out = slots @ out_W + out_b + query (f32 d_out)
// GEMM body: 64x128 tile, 4 waves (2x2, 32x64 each), 2x4 mfma 16x16x32 bf16,
// BK=32, double-buffered LDS, counted-vmcnt raw barriers.
// ---------------------------------------------------------------------------

typedef unsigned short ushort_t;
typedef unsigned int uint_t;
typedef __attribute__((ext_vector_type(8))) short bf16x8;
typedef __attribute__((ext_vector_type(4))) float f32x4;
typedef __attribute__((ext_vector_type(2))) _Float16 f16x2;

__device__ __forceinline__ float bf2f(ushort_t u) {
    return __uint_as_float(((uint_t)u) << 16);
}
__device__ __forceinline__ ushort_t f2bf(float f) {
    uint_t i = __float_as_uint(f);
    uint_t r = i + 0x7fffu + ((i >> 16) & 1u);   // round-to-nearest-even
    return (ushort_t)(r >> 16);
}
// 8x f32 -> 8x bf16 via v_cvt_pk_bf16_f32 (RNE)
__device__ __forceinline__ bf16x8 pack8(float4 v0, float4 v1) {
    union { uint_t u[4]; bf16x8 v; } r;
    asm("v_cvt_pk_bf16_f32 %0, %1, %2" : "=v"(r.u[0]) : "v"(v0.x), "v"(v0.y));
    asm("v_cvt_pk_bf16_f32 %0, %1, %2" : "=v"(r.u[1]) : "v"(v0.z), "v"(v0.w));
    asm("v_cvt_pk_bf16_f32 %0, %1, %2" : "=v"(r.u[2]) : "v"(v1.x), "v"(v1.y));
    asm("v_cvt_pk_bf16_f32 %0, %1, %2" : "=v"(r.u[3]) : "v"(v1.z), "v"(v1.w));
    return r.v;
}
__device__ __forceinline__ ushort_t f2h(float f) {
    union { _Float16 h; ushort_t u; } cv;
    cv.h = (_Float16)f;
    return cv.u;
}

// acch[0..3] (packed f16x2, 8 channels) += wp(f16x2 dup) * f16x8(v)
__device__ __forceinline__ void pk_fma8(uint_t* a, uint_t wp, const uint4& v) {
    asm("v_pk_fma_f16 %0, %1, %2, %0" : "+v"(a[0]) : "v"(wp), "v"(v.x));
    asm("v_pk_fma_f16 %0, %1, %2, %0" : "+v"(a[1]) : "v"(wp), "v"(v.y));
    asm("v_pk_fma_f16 %0, %1, %2, %0" : "+v"(a[2]) : "v"(wp), "v"(v.z));
    asm("v_pk_fma_f16 %0, %1, %2, %0" : "+v"(a[3]) : "v"(wp), "v"(v.w));
}

// 16B global -> LDS direct (async, tracked by vmcnt)
__device__ __forceinline__ void load_lds16(const void* g, void* l) {
    __builtin_amdgcn_global_load_lds(
        (const __attribute__((address_space(1))) void*)g,
        (__attribute__((address_space(3))) void*)l, 16, 0, 0);
}

// ---------------------------------------------------------------------------
// prep_w: weight transpose+convert only. W[k][N] f32 -> T[n][256] bf16.
// grid (8,16,4): z=0 value_W, z=1 out_W, z=2 off_W(512), z=3 attw_W.
// ---------------------------------------------------------------------------
__global__ __launch_bounds__(256) void prep_w(
    const float* __restrict__ Wv, const float* __restrict__ Wo,
    const float* __restrict__ Wf, const float* __restrict__ Wa,
    ushort_t* __restrict__ Tv, ushort_t* __restrict__ To,
    ushort_t* __restrict__ Tqk) {
    const int z = blockIdx.z;
    const float* W;
    ushort_t* T;
    int N;
    if (z == 0)      { W = Wv; T = Tv;              N = 256; }
    else if (z == 1) { W = Wo; T = To;              N = 256; }
    else if (z == 2) { W = Wf; T = Tqk;             N = 512; }
    else             { W = Wa; T = Tqk + 512 * 256; N = 256; }
    const int n0 = blockIdx.y * 32;
    if (n0 >= N) return;
    const int k0 = blockIdx.x * 32;

    __shared__ float tile[32][33];
    const int tx = threadIdx.x & 31;
    const int ty = threadIdx.x >> 5;   // 0..7
    #pragma unroll
    for (int r = 0; r < 4; ++r) {
        const int k = ty + r * 8;
        tile[k][tx] = W[(size_t)(k0 + k) * N + n0 + tx];
    }
    __syncthreads();
    #pragma unroll
    for (int r = 0; r < 4; ++r) {
        const int n = ty + r * 8;
        T[(size_t)(n0 + n) * 256 + k0 + tx] = f2bf(tile[tx][n]);
    }
}

// ---------------------------------------------------------------------------
// MFMA GEMM body, 64x128 tile: C[M,N] = A[M,256] @ Wt^T + bias (+resid).
// 4 waves in 2x2; each wave computes 32 rows x 64 cols (2x4 fragments).
// Staging: B via global_load_lds (LDS byte offset == t*16, wave-uniform base
// + lane*16); A: AF32 -> reg depth-3 + pack8 + ds_write; else global_load_lds.
// Barrier: s_waitcnt vmcnt(N) lgkmcnt(0) (N = ops newer than B-stage, so the
// in-flight A(k+3) HBM loads cross the barrier) + raw s_barrier.
// OUT_MODE: 0=f32, 1=bf16, 2=f16. Astride: A row stride (elements).
// Wt bf16 [N][256]. 256 threads. LDS 24KB.
// ---------------------------------------------------------------------------
template <bool AF32, int OUT_MODE, bool RESID>
__device__ __forceinline__ void gemm_body(
    ushort_t (*sA)[64][32], ushort_t (*sB)[128][32],
    const void* __restrict__ Av, int Astride, const ushort_t* __restrict__ Wt,
    const float* __restrict__ bias0, const float* __restrict__ bias1, int split,
    const float* __restrict__ resid, void* __restrict__ Cv,
    int M, int N, int bx, int by) {
    const int m0 = bx * 64;
    const int n0 = by * 128;
    const int t    = threadIdx.x;
    const int lane = t & 63;
    const int w    = t >> 6;
    const int wr   = w >> 1, wc = w & 1;   // wave grid 2x2

    const int srow = t >> 2;          // 0..63
    const int skof = (t & 3) * 8;     // 0,8,16,24

    int arow = m0 + srow;             // clamp OOB rows (dup data, store-masked)
    if (arow > M - 1) arow = M - 1;
    const float*    Af0 = (const float*)Av + (size_t)arow * Astride + skof;
    const ushort_t* Ab0 = (const ushort_t*)Av + (size_t)arow * Astride + skof;
    const ushort_t* Bp0 = Wt + (size_t)(n0 + srow) * 256 + skof;
    const ushort_t* Bp1 = Bp0 + (size_t)64 * 256;

    const float4 fz = {0.f, 0.f, 0.f, 0.f};

    f32x4 acc[2][4];
    #pragma unroll
    for (int i = 0; i < 2; ++i)
        #pragma unroll
        for (int j = 0; j < 4; ++j)
            acc[i][j] = (f32x4){0.f, 0.f, 0.f, 0.f};

    // A register generations (AF32 path): af1 = data for k+1, af2 = for k+2
    float4 af1a = fz, af1b = fz, af2a = fz, af2b = fz;

    // ---- prologue: stage tile 0 into LDS[0]; AF32: prefetch A(1),A(2) ----
    if (AF32) {
        const float4 a0a = *(const float4*)(Af0);
        const float4 a0b = *(const float4*)(Af0 + 4);
        load_lds16(Bp0, &sB[0][srow][skof]);
        load_lds16(Bp1, &sB[0][64 + srow][skof]);
        __builtin_amdgcn_sched_barrier(0);
        af1a = *(const float4*)(Af0 + 32); af1b = *(const float4*)(Af0 + 36);
        af2a = *(const float4*)(Af0 + 64); af2b = *(const float4*)(Af0 + 68);
        *(bf16x8*)(&sA[0][srow][skof]) = pack8(a0a, a0b);
        // drain B-lds (+A0 regs, older) but keep A(1),A(2) in flight
        asm volatile("s_waitcnt vmcnt(4) lgkmcnt(0)" ::: "memory");
        __builtin_amdgcn_sched_barrier(0);
        __builtin_amdgcn_s_barrier();
        __builtin_amdgcn_sched_barrier(0);
    } else {
        load_lds16(Bp0, &sB[0][srow][skof]);
        load_lds16(Bp1, &sB[0][64 + srow][skof]);
        load_lds16(Ab0, &sA[0][srow][skof]);
        asm volatile("s_waitcnt vmcnt(0)" ::: "memory");
        __builtin_amdgcn_sched_barrier(0);
        __builtin_amdgcn_s_barrier();
        __builtin_amdgcn_sched_barrier(0);
    }

    const int rl = lane & 15;
    const int kq = (lane >> 4) * 8;

    #pragma unroll
    for (int k = 0; k < 8; ++k) {
        const int buf = k & 1;
        const int nbuf = buf ^ 1;

        // ---- stage next tile (B, and A if bf16 path) via global_load_lds ----
        if (k < 7) {
            const int ko = (k + 1) * 32;
            load_lds16(Bp0 + ko, &sB[nbuf][srow][skof]);
            load_lds16(Bp1 + ko, &sB[nbuf][64 + srow][skof]);
            if (!AF32)
                load_lds16(Ab0 + ko, &sA[nbuf][srow][skof]);
        }
        __builtin_amdgcn_sched_barrier(0);   // pin: lds-stages before A regs

        // ---- AF32: issue A(k+3) register loads (cross-barrier in flight) ----
        float4 nfa = fz, nfb = fz;
        if (AF32 && k < 5) {
            const int ko = (k + 3) * 32;
            nfa = *(const float4*)(Af0 + ko);
            nfb = *(const float4*)(Af0 + ko + 4);
        }

        // ---- compute on LDS[buf] ----
        bf16x8 af[2], bfr[4];
        #pragma unroll
        for (int i = 0; i < 2; ++i)
            af[i] = *(const bf16x8*)(&sA[buf][wr * 32 + i * 16 + rl][kq]);
        #pragma unroll
        for (int j = 0; j < 4; ++j)
            bfr[j] = *(const bf16x8*)(&sB[buf][wc * 64 + j * 16 + rl][kq]);
        #pragma unroll
        for (int i = 0; i < 2; ++i)
            #pragma unroll
            for (int j = 0; j < 4; ++j)
                acc[i][j] = __builtin_amdgcn_mfma_f32_16x16x32_bf16(
                    af[i], bfr[j], acc[i][j], 0, 0, 0);

        // ---- counted gate + raw barrier ----
        if (k < 7) {
            if (AF32) {
                // write A(k+1) tile (af1 loaded 2 iters ago -> no stall)
                *(bf16x8*)(&sA[nbuf][srow][skof]) = pack8(af1a, af1b);
                if (k < 5)   // A(k+3) pair stays in flight across the barrier
                    asm volatile("s_waitcnt vmcnt(2) lgkmcnt(0)" ::: "memory");
                else
                    asm volatile("s_waitcnt vmcnt(0) lgkmcnt(0)" ::: "memory");
            } else {
                asm volatile("s_waitcnt vmcnt(0)" ::: "memory");
            }
            __builtin_amdgcn_sched_barrier(0);
            __builtin_amdgcn_s_barrier();
            __builtin_amdgcn_sched_barrier(0);
            if (AF32) {
                af1a = af2a; af1b = af2b;
                af2a = nfa;  af2b = nfb;
            }
        }
    }

    // --- epilogue: C/D layout col=lane&15, row=(lane>>4)*4+reg (m89) ---
    const int col_l = lane & 15;
    const int rq    = (lane >> 4) * 4;
    #pragma unroll
    for (int j = 0; j < 4; ++j) {
        const int gn = n0 + wc * 64 + j * 16 + col_l;
        const float bj = (gn < split) ? bias0[gn] : bias1[gn - split];
        #pragma unroll
        for (int i = 0; i < 2; ++i) {
            #pragma unroll
            for (int r = 0; r < 4; ++r) {
                const int gm = m0 + wr * 32 + i * 16 + rq + r;
                if (gm >= M) continue;
                float v = acc[i][j][r] + bj;
                if (RESID) v += resid[(size_t)gm * N + gn];
                if (OUT_MODE == 1)
                    ((ushort_t*)Cv)[(size_t)gm * N + gn] = f2bf(v);
                else if (OUT_MODE == 2)
                    ((ushort_t*)Cv)[(size_t)gm * N + gn] = f2h(v);
                else
                    ((float*)Cv)[(size_t)gm * N + gn] = v;
            }
        }
    }
}

// Fused independent GEMMs: blocks [0,1020) -> vproj (510m x 2n, f16 out),
//                          [1020,1962) -> qkcat (157m x 6n, bf16 out).
__global__ __launch_bounds__(256) void gemm_vqk(
    const float* __restrict__ value, const ushort_t* __restrict__ value_Wt,
    const float* __restrict__ value_b, ushort_t* __restrict__ vproj,
    const float* __restrict__ query, const ushort_t* __restrict__ qk_Wt,
    const float* __restrict__ off_b, const float* __restrict__ attw_b,
    ushort_t* __restrict__ qkcat) {
    __shared__ ushort_t sA[2][64][32];
    __shared__ ushort_t sB[2][128][32];
    int b = blockIdx.x;
    if (b < 1020) {
        gemm_body<true, 2, false>(sA, sB, value, 256, value_Wt, value_b,
                                  value_b, 256, nullptr, (void*)vproj,
                                  32640, 256, b >> 1, b & 1);
    } else {
        b -= 1020;
        gemm_body<true, 1, false>(sA, sB, query, 256, qk_Wt, off_b, attw_b,
                                  512, nullptr, (void*)qkcat, 10000, 768,
                                  b / 6, b % 6);
    }
}

__global__ __launch_bounds__(256) void gemm_out_k(
    const ushort_t* __restrict__ slots,   // = qkcat + 512, row stride 768
    const ushort_t* __restrict__ out_Wt,
    const float* __restrict__ out_b, const float* __restrict__ query,
    float* __restrict__ out) {
    __shared__ ushort_t sA[2][64][32];
    __shared__ ushort_t sB[2][128][32];
    const int b = blockIdx.x;
    gemm_body<false, 0, true>(sA, sB, slots, 768, out_Wt, out_b, out_b, 256,
                              query, (void*)out, 10000, 256, b >> 1, b & 1);
}

// ---------------------------------------------------------------------------
// Deformable sampling (R12 structure, proven 149.5us = 71% of the L2
// random-64B-gather ceiling). grid (10000, 2), 128 thr (4 heads,
// hb = blockIdx.y*4). Barrier-free, LDS-free; slice reduction via shfl_xor
// tree; slots packed to one 16B store per writer lane into qkcat[:,512:768).
// ---------------------------------------------------------------------------
__global__ __launch_bounds__(128) void sample_k(
    ushort_t* __restrict__ qkcat,        // bf16 [10000, 768]
    const float* __restrict__ refp,      // f32 [6,1,10000,4,2]
    const int* __restrict__ vox,         // int32 [6,1,10000,4]
    const ushort_t* __restrict__ vproj) {// f16 [6*5440, 256]
    const int q    = blockIdx.x;
    const int hb   = blockIdx.y << 2;    // head base: 0 or 4
    const int tid  = threadIdx.x;        // 0..127
    const int lane = tid & 63;
    const int h    = hb + (tid >> 5);    // this thread's head
    const int lp   = tid & 31;           // setup role: (lvl,p)
    const int slice = (tid >> 2) & 7;    // gather role
    const int g     = tid & 3;           // gather role: channels g*8..g*8+7

    // ---- validity: lanes 0..5 load their cam's vox row, broadcast ----
    int mm = 0;
    if (lane < 6) {
        const uint4 vm = *(const uint4*)(vox + ((lane * 10000 + q) << 2));
        mm = (int)(vm.x | vm.y | vm.z | vm.w);
    }
    float sv[6];
    #pragma unroll
    for (int c = 0; c < 6; ++c) sv[c] = __shfl(mm, c) ? 1.0f : 0.0f;
    const float cnt = sv[0] + sv[1] + sv[2] + sv[3] + sv[4] + sv[5];

    // ---- softmax over 32 (lvl,p) entries within this head ----
    const float a = bf2f(qkcat[(size_t)q * 768 + 512 + h * 32 + lp]);
    float mx = a;
    #pragma unroll
    for (int o = 16; o >= 1; o >>= 1) mx = fmaxf(mx, __shfl_xor(mx, o));
    const float e = __expf(a - mx);
    float se = e;
    #pragma unroll
    for (int o = 16; o >= 1; o >>= 1) se += __shfl_xor(se, o);
    const float aw = e / se;

    // ---- camera-independent part of this thread's sample location ----
    const int lvl = lp >> 3;
    const int p   = lp & 7;
    const int dd  = p & 3;
    const int   Sarr[4]   = {64, 32, 16, 8};
    const int   Lstart[4] = {0, 4096, 5120, 5376};
    const int   S  = Sarr[lvl];
    const float Sf = (float)S;
    const int   lstart = Lstart[lvl];
    const int   hoff   = h << 6;     // head byte offset within a row (32ch*2B)
    const float ox = bf2f(qkcat[(size_t)q * 768 + h * 64 + lvl * 16 + p * 2 + 0]) / Sf;
    const float oy = bf2f(qkcat[(size_t)q * 768 + h * 64 + lvl * 16 + p * 2 + 1]) / Sf;

    float acc[8] = {0.f, 0.f, 0.f, 0.f, 0.f, 0.f, 0.f, 0.f};
    const char* vpb = (const char*)vproj;
    const int goff = g << 4;             // 4 lanes x 16B within 64B chunk
    const int srcbase = (lane & 32) + slice * 4;

    for (int c = 0; c < 6; ++c) {
        if (sv[c] == 0.0f) continue;     // block-uniform branch

        // ---- setup: corner BYTE offsets + packed-f16 weights ----
        int    cb[4];
        uint_t cwp[4];
        {
            const int cbase = c * 5440 + lstart;
            const int rbase = ((c * 10000 + q) * 4 + dd) * 2;
            const float rx = refp[rbase + 0];
            const float ry = refp[rbase + 1];
            const float x  = (rx + ox) * Sf - 0.5f;
            const float y  = (ry + oy) * Sf - 0.5f;
            const float x0 = floorf(x), y0 = floorf(y);
            #pragma unroll
            for (int k = 0; k < 4; ++k) {
                const float cx = x0 + (float)(k & 1);
                const float cy = y0 + (float)(k >> 1);
                const float wgt = (1.0f - fabsf(x - cx)) * (1.0f - fabsf(y - cy));
                const bool ok = (cx >= 0.0f) & (cx < Sf) & (cy >= 0.0f) & (cy < Sf);
                const int xi = (int)fminf(fmaxf(cx, 0.0f), Sf - 1.0f);
                const int yi = (int)fminf(fmaxf(cy, 0.0f), Sf - 1.0f);
                cb[k] = ((cbase + yi * S + xi) << 9) + hoff;   // bytes
                const float cw = ok ? wgt * aw : 0.0f;
                const uint_t hw = (uint_t)f2h(cw);
                cwp[k] = (hw << 16) | hw;                      // f16 dup
            }
        }

        // ---- exchange byte offsets for all 4 groups ----
        int b[4][4];
        #pragma unroll
        for (int j = 0; j < 4; ++j) {
            const int src = srcbase + j;
            b[j][0] = __shfl(cb[0], src);
            b[j][1] = __shfl(cb[1], src);
            b[j][2] = __shfl(cb[2], src);
            b[j][3] = __shfl(cb[3], src);
        }

        // ---- depth-2 pipelined gather: group j+1 in flight during j ----
        uint_t acch[4] = {0u, 0u, 0u, 0u};   // packed f16x2, 8 channels
        uint4 v0 = *(const uint4*)(vpb + (b[0][0] + goff));
        uint4 v1 = *(const uint4*)(vpb + (b[0][1] + goff));
        uint4 v2 = *(const uint4*)(vpb + (b[0][2] + goff));
        uint4 v3 = *(const uint4*)(vpb + (b[0][3] + goff));
        #pragma unroll
        for (int j = 0; j < 4; ++j) {
            uint4 n0 = v0, n1 = v1, n2 = v2, n3 = v3;
            if (j < 3) {
                n0 = *(const uint4*)(vpb + (b[j + 1][0] + goff));
                n1 = *(const uint4*)(vpb + (b[j + 1][1] + goff));
                n2 = *(const uint4*)(vpb + (b[j + 1][2] + goff));
                n3 = *(const uint4*)(vpb + (b[j + 1][3] + goff));
            }
            const int src = srcbase + j;
            const uint_t w0 = (uint_t)__shfl((int)cwp[0], src);
            const uint_t w1 = (uint_t)__shfl((int)cwp[1], src);
            const uint_t w2 = (uint_t)__shfl((int)cwp[2], src);
            const uint_t w3 = (uint_t)__shfl((int)cwp[3], src);
            pk_fma8(acch, w0, v0);
            pk_fma8(acch, w1, v1);
            pk_fma8(acch, w2, v2);
            pk_fma8(acch, w3, v3);
            v0 = n0; v1 = n1; v2 = n2; v3 = n3;
        }

        // ---- drain packed f16 accumulators to f32 (once per camera) ----
        #pragma unroll
        for (int n = 0; n < 4; ++n) {
            union { uint_t u; f16x2 h; } cvu;
            cvu.u = acch[n];
            acc[2 * n]     += (float)cvu.h.x;
            acc[2 * n + 1] += (float)cvu.h.y;
        }
    }

    // ---- cross-slice reduction: shfl_xor tree over slice bits (4/8/16) ----
    #pragma unroll
    for (int n = 0; n < 8; ++n) {
        acc[n] += __shfl_xor(acc[n], 4);
        acc[n] += __shfl_xor(acc[n], 8);
        acc[n] += __shfl_xor(acc[n], 16);
    }

    // ---- slot write: slice==0 lanes pack 8 channels -> one 16B store ----
    if (slice == 0) {
        const float inv = 1.0f / fmaxf(cnt, 1.0f);
        uint4 r;
        asm("v_cvt_pk_bf16_f32 %0, %1, %2"
            : "=v"(r.x) : "v"(acc[0] * inv), "v"(acc[1] * inv));
        asm("v_cvt_pk_bf16_f32 %0, %1, %2"
            : "=v"(r.y) : "v"(acc[2] * inv), "v"(acc[3] * inv));
        asm("v_cvt_pk_bf16_f32 %0, %1, %2"
            : "=v"(r.z) : "v"(acc[4] * inv), "v"(acc[5] * inv));
        asm("v_cvt_pk_bf16_f32 %0, %1, %2"
            : "=v"(r.w) : "v"(acc[6] * inv), "v"(acc[7] * inv));
        *(uint4*)(&qkcat[(size_t)q * 768 + 512 + h * 32 + g * 8]) = r;
    }
}

// ---------------------------------------------------------------------------
extern "C" void kernel_launch(void* const* d_in, const int* in_sizes, int n_in,
                              void* d_out, int out_size, void* d_ws, size_t ws_size,
                              hipStream_t stream) {
    const float* query   = (const float*)d_in[0];
    // d_in[1] = key : unused by the deformable-attention math
    const float* value   = (const float*)d_in[2];   // (6,5440,1,256) -> (32640,256)
    const float* refp    = (const float*)d_in[3];
    const int*   vox     = (const int*)d_in[4];
    // d_in[5] spatial_shapes, d_in[6] level_start_index : compile-time constants
    const float* value_W = (const float*)d_in[7];
    const float* value_b = (const float*)d_in[8];
    const float* off_W   = (const float*)d_in[9];
    const float* off_b   = (const float*)d_in[10];
    const float* attw_W  = (const float*)d_in[11];
    const float* attw_b  = (const float*)d_in[12];
    const float* out_W   = (const float*)d_in[13];
    const float* out_b   = (const float*)d_in[14];
    float* out = (float*)d_out;

    // ws layout (bytes):
    //   [0,        16711680)  vproj f16 [32640][256]
    //   [16711680, 32071680)  qkcat bf16 [10000][768] (slots in cols 512..768)
    //   [32071680, 32727040)  value_Wt | out_Wt | qk_Wt  bf16
    char* ws = (char*)d_ws;
    ushort_t* vproj    = (ushort_t*)ws;
    ushort_t* qkcat    = (ushort_t*)(ws + 16711680);
    ushort_t* value_Wt = (ushort_t*)(ws + 32071680);
    ushort_t* out_Wt   = (ushort_t*)(ws + 32071680 + 131072);
    ushort_t* qk_Wt    = (ushort_t*)(ws + 32071680 + 262144);

    // 1. weight transpose+convert -> Wt[n][k] bf16
    prep_w<<<dim3(8, 16, 4), 256, 0, stream>>>(
        value_W, out_W, off_W, attw_W, value_Wt, out_Wt, qk_Wt);
    // 2. fused value-proj (f16 out) + offset/attw-proj (bf16 out), 64x128 tiles
    gemm_vqk<<<1962, 256, 0, stream>>>(value, value_Wt, value_b, vproj,
                                       query, qk_Wt, off_b, attw_b, qkcat);
    // 3. deformable sampling + softmax + camera mask/count -> slots in qkcat
    sample_k<<<dim3(10000, 2), 128, 0, stream>>>(qkcat, refp, vox, vproj);
    // 4. output projection + residual, f32 out
    gemm_out_k<<<314, 256, 0, stream>>>(qkcat + 512, out_Wt, out_b,
                                        query, out);
}